// Round 8
// baseline (228.414 us; speedup 1.0000x reference)
//
#include <hip/hip_runtime.h>
#include <hip/hip_bf16.h>
#include <math.h>

#define MEM_DIM 1024
#define N_CHILD 16384

#define BM 128          // n-rows per block
#define BN 64           // j-cols per block
#define BK 64
#define KITERS (MEM_DIM / BK)

typedef __bf16 bf16_t;
typedef __bf16 bf16x4 __attribute__((ext_vector_type(4)));
typedef __bf16 bf16x8 __attribute__((ext_vector_type(8)));
typedef float f32x4 __attribute__((ext_vector_type(4)));

__device__ __forceinline__ void async_load16(const bf16_t* g, bf16_t* l) {
    __builtin_amdgcn_global_load_lds(
        (const __attribute__((address_space(1))) unsigned int*)g,
        (__attribute__((address_space(3))) unsigned int*)l,
        16, 0, 0);
}

// ---------------- Kernel 0: prep = gates matvecs (blocks 0..1023) + fp32->bf16 cvt ----
// cvt dst: [child_h bf16 row-major][W_fh bf16 row-major] contiguous.
__global__ __launch_bounds__(256) void prep_kernel(
        const float* __restrict__ child_h, const float* __restrict__ W_fh,
        bf16_t* __restrict__ dst, int n8,
        const float* __restrict__ hsum,
        const float* __restrict__ W_ih, const float* __restrict__ b_ih,
        const float* __restrict__ W_uh, const float* __restrict__ b_uh,
        const float* __restrict__ W_oh, const float* __restrict__ b_oh,
        float* __restrict__ acc_c, float* __restrict__ o_ws) {
    const int tid = threadIdx.x;
    if (blockIdx.x < MEM_DIM) {
        // ---- gates: one block per output column j ----
        const int j = blockIdx.x;
        const float* wi = W_ih + (size_t)j * MEM_DIM;
        const float* wu = W_uh + (size_t)j * MEM_DIM;
        const float* wo = W_oh + (size_t)j * MEM_DIM;
        float si = 0.f, su = 0.f, so = 0.f;
        for (int k = tid; k < MEM_DIM; k += 256) {
            float hv = hsum[k];
            si += wi[k] * hv;
            su += wu[k] * hv;
            so += wo[k] * hv;
        }
        for (int off = 32; off > 0; off >>= 1) {
            si += __shfl_down(si, off, 64);
            su += __shfl_down(su, off, 64);
            so += __shfl_down(so, off, 64);
        }
        __shared__ float red[3][4];
        const int wave = tid >> 6, lane = tid & 63;
        if (lane == 0) { red[0][wave] = si; red[1][wave] = su; red[2][wave] = so; }
        __syncthreads();
        if (tid == 0) {
            float ti = red[0][0] + red[0][1] + red[0][2] + red[0][3] + b_ih[j];
            float tu = red[1][0] + red[1][1] + red[1][2] + red[1][3] + b_uh[j];
            float to = red[2][0] + red[2][1] + red[2][2] + red[2][3] + b_oh[j];
            float iv = 1.f / (1.f + expf(-ti));
            float uv = tanhf(tu);
            float ov = 1.f / (1.f + expf(-to));
            acc_c[j] = iv * uv;     // accumulator init with i*u
            o_ws[j]  = ov;
        }
    } else {
        // ---- cvt: thread handles 8 consecutive elems ----
        const int nA8 = (N_CHILD * MEM_DIM) / 8;
        int t = (blockIdx.x - MEM_DIM) * 256 + tid;
        if (t < n8) {
            const float* s = (t < nA8) ? (child_h + (size_t)t * 8)
                                       : (W_fh + (size_t)(t - nA8) * 8);
            float4 a = *(const float4*)s;
            float4 b = *(const float4*)(s + 4);
            bf16x8 o = { (bf16_t)a.x, (bf16_t)a.y, (bf16_t)a.z, (bf16_t)a.w,
                         (bf16_t)b.x, (bf16_t)b.y, (bf16_t)b.z, (bf16_t)b.w };
            *(bf16x8*)(dst + (size_t)t * 8) = o;
        }
    }
}

// ---------------- Kernel 1: fused f-gate GEMM + column reduction ----------------
// R4 structure (session-best GEMM): 128n x 64j tile, 4 waves 2x2 (wave = 64n x 32j),
// BK=64, swizzled LDS, global_load_lds x16 — PLUS child_c/bias register prefetch
// before the K-loop so the epilogue has no cold HBM reads (tail removal).
__global__ __launch_bounds__(256, 4) void fused_gemm_bf16(
        const bf16_t* __restrict__ hbf, const bf16_t* __restrict__ wbf,
        const float* __restrict__ child_c, const float* __restrict__ b_fh,
        float* __restrict__ acc_c) {
    __shared__ __align__(1024) bf16_t sA[BM * BK];   // 16 KB
    __shared__ __align__(1024) bf16_t sB[BN * BK];   // 8 KB
    __shared__ float sred[BN];

    const int tid  = threadIdx.x;
    const int lane = tid & 63;
    const int wave = tid >> 6;
    const int wr = wave >> 1;        // n-half (64 rows)
    const int wc = wave & 1;         // j-half (32 cols)
    const int q  = lane >> 4;
    const int cl = lane & 15;

    // XCD-aware tile mapping: 2048 blocks, xcd = b&7; j sweeps fastest within
    // an XCD so 16 consecutive same-XCD blocks share one A-tile (L2-local).
    const int b   = blockIdx.x;
    const int xcd = b & 7;
    const int l   = b >> 3;          // 0..255
    const int jt  = l & 15;
    const int ntl = l >> 4;          // 0..15
    const int j0  = jt * BN;
    const int n0  = (xcd * 16 + ntl) * BM;

    // --- staging addresses ---
    const int rl = lane >> 3;        // row within an 8-row issue group
    const int p  = lane & 7;         // chunk slot this lane fills
    const int cf = (p ^ rl) * 8;     // fetched chunk's column (swz(r) = r&7 = rl)
    const bf16_t* gA[4];
    bf16_t* lA[4];
#pragma unroll
    for (int i = 0; i < 4; i++) {    // A: 128 rows, wave covers rows [wave*32, wave*32+32)
        const int r = wave * 32 + i * 8 + rl;
        gA[i] = hbf + (size_t)(n0 + r) * MEM_DIM + cf;
        lA[i] = &sA[(wave * 32 + i * 8) * BK];
    }
    const bf16_t* gB[2];
    bf16_t* lB[2];
#pragma unroll
    for (int i = 0; i < 2; i++) {    // B: 64 rows, wave covers rows [wave*16, wave*16+16)
        const int r = wave * 16 + i * 8 + rl;
        gB[i] = wbf + (size_t)(j0 + r) * MEM_DIM + cf;
        lB[i] = &sB[(wave * 16 + i * 8) * BK];
    }

    f32x4 acc[4][2];
#pragma unroll
    for (int a = 0; a < 4; a++)
#pragma unroll
        for (int c = 0; c < 2; c++) acc[a][c] = (f32x4)0.0f;

    // --- prefetch: child_c tile elements + bias into registers; these loads
    // ride the vmcnt queue and are drained by the iter-0 barrier, hiding the
    // epilogue's HBM tail behind the K-loop. ---
    float ccr[2][4][4];
    float biasr[2];
    {
        const float* ccp = child_c + (size_t)(n0 + wr * 64 + q * 4) * MEM_DIM
                                   + j0 + wc * 32 + cl;
#pragma unroll
        for (int nt = 0; nt < 2; nt++) {
            biasr[nt] = b_fh[j0 + wc * 32 + nt * 16 + cl];
#pragma unroll
            for (int mt = 0; mt < 4; mt++)
#pragma unroll
                for (int r = 0; r < 4; r++)
                    ccr[nt][mt][r] = ccp[(size_t)(mt * 16 + r) * MEM_DIM + nt * 16];
        }
    }

    for (int k = 0; k < KITERS; ++k) {
#pragma unroll
        for (int i = 0; i < 4; i++) { async_load16(gA[i], lA[i]); gA[i] += BK; }
#pragma unroll
        for (int i = 0; i < 2; i++) { async_load16(gB[i], lB[i]); gB[i] += BK; }
        __syncthreads();   // drain: LDS tiles ready

#pragma unroll
        for (int h = 0; h < 2; h++) {
            bf16x8 af[4], bfr[2];
#pragma unroll
            for (int mt = 0; mt < 4; mt++) {
                const int ra = wr * 64 + mt * 16 + cl;
                af[mt] = *(const bf16x8*)(&sA[ra * BK + (((4 * h + q) ^ (cl & 7)) * 8)]);
            }
#pragma unroll
            for (int nt = 0; nt < 2; nt++) {
                const int rb = wc * 32 + nt * 16 + cl;
                bfr[nt] = *(const bf16x8*)(&sB[rb * BK + (((4 * h + q) ^ (cl & 7)) * 8)]);
            }
#pragma unroll
            for (int mt = 0; mt < 4; mt++)
#pragma unroll
                for (int nt = 0; nt < 2; nt++)
                    acc[mt][nt] = __builtin_amdgcn_mfma_f32_16x16x32_bf16(
                        af[mt], bfr[nt], acc[mt][nt], 0, 0, 0);
        }
        __syncthreads();   // tiles consumed
    }

    // --- epilogue: f = sigmoid(S+b), colsum over 128 rows — all operands in regs ---
    if (tid < BN) sred[tid] = 0.0f;
    __syncthreads();

    float colsum[2] = {0.f, 0.f};
#pragma unroll
    for (int nt = 0; nt < 2; nt++) {
#pragma unroll
        for (int mt = 0; mt < 4; mt++) {
#pragma unroll
            for (int r = 0; r < 4; r++) {
                // C/D layout: col = lane&15, row = q*4 + r
                float s = acc[mt][nt][r] + biasr[nt];
                float fg = 1.0f / (1.0f + __expf(-s));
                colsum[nt] += fg * ccr[nt][mt][r];
            }
        }
        colsum[nt] += __shfl_xor(colsum[nt], 16, 64);
        colsum[nt] += __shfl_xor(colsum[nt], 32, 64);
    }
    if (q == 0) {
#pragma unroll
        for (int nt = 0; nt < 2; nt++)
            atomicAdd(&sred[wc * 32 + nt * 16 + cl], colsum[nt]);
    }
    __syncthreads();
    if (tid < BN) atomicAdd(&acc_c[j0 + tid], sred[tid]);
}

// ---------------- Kernel 2: finalize c, h ----------------
__global__ void finalize_kernel(const float* __restrict__ acc_c,
                                const float* __restrict__ o_ws,
                                float* __restrict__ out) {
    int t = blockIdx.x * 256 + threadIdx.x;
    if (t < MEM_DIM) {
        float cv = acc_c[t];
        float hv = o_ws[t] * tanhf(cv);
        out[t] = cv;
        out[MEM_DIM + t] = hv;
    }
}

// ---------------- Fallback path (ws too small) ----------------
__global__ void gates_kernel(const float* __restrict__ hsum,
                             const float* __restrict__ W_ih, const float* __restrict__ b_ih,
                             const float* __restrict__ W_uh, const float* __restrict__ b_uh,
                             const float* __restrict__ W_oh, const float* __restrict__ b_oh,
                             float* __restrict__ acc_c, float* __restrict__ o_ws) {
    const int j = blockIdx.x;
    const int tid = threadIdx.x;
    const float* wi = W_ih + (size_t)j * MEM_DIM;
    const float* wu = W_uh + (size_t)j * MEM_DIM;
    const float* wo = W_oh + (size_t)j * MEM_DIM;
    float si = 0.f, su = 0.f, so = 0.f;
    for (int k = tid; k < MEM_DIM; k += 256) {
        float hv = hsum[k];
        si += wi[k] * hv;
        su += wu[k] * hv;
        so += wo[k] * hv;
    }
    for (int off = 32; off > 0; off >>= 1) {
        si += __shfl_down(si, off, 64);
        su += __shfl_down(su, off, 64);
        so += __shfl_down(so, off, 64);
    }
    __shared__ float red[3][4];
    const int wave = tid >> 6, lane = tid & 63;
    if (lane == 0) { red[0][wave] = si; red[1][wave] = su; red[2][wave] = so; }
    __syncthreads();
    if (tid == 0) {
        float ti = red[0][0] + red[0][1] + red[0][2] + red[0][3] + b_ih[j];
        float tu = red[1][0] + red[1][1] + red[1][2] + red[1][3] + b_uh[j];
        float to = red[2][0] + red[2][1] + red[2][2] + red[2][3] + b_oh[j];
        acc_c[j] = (1.f / (1.f + expf(-ti))) * tanhf(tu);
        o_ws[j]  = 1.f / (1.f + expf(-to));
    }
}

#define LDS_STRIDE 40
__global__ __launch_bounds__(256) void fused_gemm_f32(
        const float* __restrict__ child_h, const float* __restrict__ child_c,
        const float* __restrict__ W_fh, const float* __restrict__ b_fh,
        float* __restrict__ acc_c) {
    __shared__ __align__(16) bf16_t sA[128 * LDS_STRIDE];
    __shared__ __align__(16) bf16_t sB[128 * LDS_STRIDE];
    __shared__ float sred[128];
    const int tid = threadIdx.x, lane = tid & 63, wave = tid >> 6;
    const int wr = wave >> 1, wc = wave & 1;
    const int j0 = blockIdx.x * 128, n0 = blockIdx.y * 128;
    const int q = lane >> 4, cl = lane & 15;
    f32x4 acc[4][4];
#pragma unroll
    for (int a = 0; a < 4; a++)
#pragma unroll
        for (int c = 0; c < 4; c++) acc[a][c] = (f32x4)0.0f;
    for (int k0 = 0; k0 < MEM_DIM; k0 += 32) {
#pragma unroll
        for (int i = 0; i < 4; i++) {
            int f = tid + i * 256, row = f >> 3, col = (f & 7) * 4;
            float4 va = *(const float4*)(child_h + (size_t)(n0 + row) * MEM_DIM + k0 + col);
            float4 vb = *(const float4*)(W_fh    + (size_t)(j0 + row) * MEM_DIM + k0 + col);
            bf16x4 ba = { (bf16_t)va.x, (bf16_t)va.y, (bf16_t)va.z, (bf16_t)va.w };
            bf16x4 bb = { (bf16_t)vb.x, (bf16_t)vb.y, (bf16_t)vb.z, (bf16_t)vb.w };
            *(bf16x4*)(&sA[row * LDS_STRIDE + col]) = ba;
            *(bf16x4*)(&sB[row * LDS_STRIDE + col]) = bb;
        }
        __syncthreads();
        bf16x8 af[4], bfr[4];
#pragma unroll
        for (int mt = 0; mt < 4; mt++) {
            af[mt]  = *(const bf16x8*)(&sA[(wr * 64 + mt * 16 + cl) * LDS_STRIDE + q * 8]);
            bfr[mt] = *(const bf16x8*)(&sB[(wc * 64 + mt * 16 + cl) * LDS_STRIDE + q * 8]);
        }
#pragma unroll
        for (int mt = 0; mt < 4; mt++)
#pragma unroll
            for (int nt = 0; nt < 4; nt++)
                acc[mt][nt] = __builtin_amdgcn_mfma_f32_16x16x32_bf16(af[mt], bfr[nt], acc[mt][nt], 0, 0, 0);
        __syncthreads();
    }
    if (tid < 128) sred[tid] = 0.0f;
    __syncthreads();
    float colsum[4] = {0.f, 0.f, 0.f, 0.f};
#pragma unroll
    for (int nt = 0; nt < 4; nt++) {
        const int col = j0 + wc * 64 + nt * 16 + cl;
        const float bias = b_fh[col];
#pragma unroll
        for (int mt = 0; mt < 4; mt++)
#pragma unroll
            for (int r = 0; r < 4; r++) {
                const int row = n0 + wr * 64 + mt * 16 + q * 4 + r;
                float s = acc[mt][nt][r] + bias;
                float fg = 1.0f / (1.0f + __expf(-s));
                colsum[nt] += fg * child_c[(size_t)row * MEM_DIM + col];
            }
        colsum[nt] += __shfl_xor(colsum[nt], 16, 64);
        colsum[nt] += __shfl_xor(colsum[nt], 32, 64);
    }
    if (q == 0)
#pragma unroll
        for (int nt = 0; nt < 4; nt++)
            atomicAdd(&sred[wc * 64 + nt * 16 + cl], colsum[nt]);
    __syncthreads();
    if (tid < 128) atomicAdd(&acc_c[j0 + tid], sred[tid]);
}

extern "C" void kernel_launch(void* const* d_in, const int* in_sizes, int n_in,
                              void* d_out, int out_size, void* d_ws, size_t ws_size,
                              hipStream_t stream) {
    const float* child_c = (const float*)d_in[0];
    const float* child_h = (const float*)d_in[1];
    const float* hsum    = (const float*)d_in[2];
    const float* W_ih    = (const float*)d_in[3];
    const float* b_ih    = (const float*)d_in[4];
    const float* W_fh    = (const float*)d_in[5];
    const float* b_fh    = (const float*)d_in[6];
    const float* W_uh    = (const float*)d_in[7];
    const float* b_uh    = (const float*)d_in[8];
    const float* W_oh    = (const float*)d_in[9];
    const float* b_oh    = (const float*)d_in[10];
    float* out   = (float*)d_out;

    float* acc_c = (float*)d_ws;                         // 1024 f
    float* o_ws  = acc_c + MEM_DIM;                      // 1024 f
    const size_t HBF_OFF   = 8192;                       // bytes
    const size_t HBF_BYTES = (size_t)N_CHILD * MEM_DIM * 2;   // 33.5 MB
    const size_t WBF_BYTES = (size_t)MEM_DIM * MEM_DIM * 2;   // 2 MB
    const size_t NEED = HBF_OFF + HBF_BYTES + WBF_BYTES;

    if (ws_size >= NEED) {
        bf16_t* hbf = (bf16_t*)((char*)d_ws + HBF_OFF);
        bf16_t* wbf = hbf + (size_t)N_CHILD * MEM_DIM;
        const int n8 = (N_CHILD * MEM_DIM + MEM_DIM * MEM_DIM) / 8;  // 2,228,224
        const int cvtBlocks = (n8 + 255) / 256;                      // 8704
        prep_kernel<<<MEM_DIM + cvtBlocks, 256, 0, stream>>>(
            child_h, W_fh, hbf, n8,
            hsum, W_ih, b_ih, W_uh, b_uh, W_oh, b_oh, acc_c, o_ws);
        fused_gemm_bf16<<<(N_CHILD / BM) * (MEM_DIM / BN), 256, 0, stream>>>(
            hbf, wbf, child_c, b_fh, acc_c);
    } else {
        gates_kernel<<<MEM_DIM, 256, 0, stream>>>(hsum, W_ih, b_ih, W_uh, b_uh,
                                                  W_oh, b_oh, acc_c, o_ws);
        dim3 grid(MEM_DIM / 128, N_CHILD / 128);
        fused_gemm_f32<<<grid, 256, 0, stream>>>(child_h, child_c, W_fh, b_fh, acc_c);
    }
    finalize_kernel<<<(MEM_DIM + 255) / 256, 256, 0, stream>>>(acc_c, o_ws, out);
}

// Round 9
// 213.253 us; speedup vs baseline: 1.0711x; 1.0711x over previous
//
#include <hip/hip_runtime.h>
#include <hip/hip_bf16.h>
#include <math.h>

#define MEM_DIM 1024
#define N_CHILD 16384

#define BM 128          // n-rows per block
#define BN 64           // j-cols per block
#define BK 64
#define KITERS (MEM_DIM / BK)

typedef __bf16 bf16_t;
typedef __bf16 bf16x4 __attribute__((ext_vector_type(4)));
typedef __bf16 bf16x8 __attribute__((ext_vector_type(8)));
typedef float f32x4 __attribute__((ext_vector_type(4)));

__device__ __forceinline__ void async_load16(const bf16_t* g, bf16_t* l) {
    __builtin_amdgcn_global_load_lds(
        (const __attribute__((address_space(1))) unsigned int*)g,
        (__attribute__((address_space(3))) unsigned int*)l,
        16, 0, 0);
}

// ---------------- Kernel 0: prep = gates matvecs (blocks 0..1023) + fp32->bf16 cvt ----
__global__ __launch_bounds__(256) void prep_kernel(
        const float* __restrict__ child_h, const float* __restrict__ W_fh,
        bf16_t* __restrict__ dst, int n8,
        const float* __restrict__ hsum,
        const float* __restrict__ W_ih, const float* __restrict__ b_ih,
        const float* __restrict__ W_uh, const float* __restrict__ b_uh,
        const float* __restrict__ W_oh, const float* __restrict__ b_oh,
        float* __restrict__ acc_c, float* __restrict__ o_ws) {
    const int tid = threadIdx.x;
    if (blockIdx.x < MEM_DIM) {
        // ---- gates: one block per output column j ----
        const int j = blockIdx.x;
        const float* wi = W_ih + (size_t)j * MEM_DIM;
        const float* wu = W_uh + (size_t)j * MEM_DIM;
        const float* wo = W_oh + (size_t)j * MEM_DIM;
        float si = 0.f, su = 0.f, so = 0.f;
        for (int k = tid; k < MEM_DIM; k += 256) {
            float hv = hsum[k];
            si += wi[k] * hv;
            su += wu[k] * hv;
            so += wo[k] * hv;
        }
        for (int off = 32; off > 0; off >>= 1) {
            si += __shfl_down(si, off, 64);
            su += __shfl_down(su, off, 64);
            so += __shfl_down(so, off, 64);
        }
        __shared__ float red[3][4];
        const int wave = tid >> 6, lane = tid & 63;
        if (lane == 0) { red[0][wave] = si; red[1][wave] = su; red[2][wave] = so; }
        __syncthreads();
        if (tid == 0) {
            float ti = red[0][0] + red[0][1] + red[0][2] + red[0][3] + b_ih[j];
            float tu = red[1][0] + red[1][1] + red[1][2] + red[1][3] + b_uh[j];
            float to = red[2][0] + red[2][1] + red[2][2] + red[2][3] + b_oh[j];
            float iv = 1.f / (1.f + expf(-ti));
            float uv = tanhf(tu);
            float ov = 1.f / (1.f + expf(-to));
            acc_c[j] = iv * uv;     // accumulator init with i*u
            o_ws[j]  = ov;
        }
    } else {
        // ---- cvt: thread handles 8 consecutive elems ----
        const int nA8 = (N_CHILD * MEM_DIM) / 8;
        int t = (blockIdx.x - MEM_DIM) * 256 + tid;
        if (t < n8) {
            const float* s = (t < nA8) ? (child_h + (size_t)t * 8)
                                       : (W_fh + (size_t)(t - nA8) * 8);
            float4 a = *(const float4*)s;
            float4 b = *(const float4*)(s + 4);
            bf16x8 o = { (bf16_t)a.x, (bf16_t)a.y, (bf16_t)a.z, (bf16_t)a.w,
                         (bf16_t)b.x, (bf16_t)b.y, (bf16_t)b.z, (bf16_t)b.w };
            *(bf16x8*)(dst + (size_t)t * 8) = o;
        }
    }
}

// ---------------- Kernel 1: fused f-gate GEMM + column reduction ----------------
// R4 structure (session-best): 128n x 64j tile, 4 waves 2x2 (wave = 64n x 32j),
// BK=64, swizzled LDS, global_load_lds x16. Last K-iteration PEELED: child_c +
// bias loads issue with the last staging loads, drained by the same barrier ->
// epilogue has no cold HBM reads. No min-waves bound (avoid R8's spill).
__global__ __launch_bounds__(256) void fused_gemm_bf16(
        const bf16_t* __restrict__ hbf, const bf16_t* __restrict__ wbf,
        const float* __restrict__ child_c, const float* __restrict__ b_fh,
        float* __restrict__ acc_c) {
    __shared__ __align__(1024) bf16_t sA[BM * BK];   // 16 KB
    __shared__ __align__(1024) bf16_t sB[BN * BK];   // 8 KB
    __shared__ float sred[BN];

    const int tid  = threadIdx.x;
    const int lane = tid & 63;
    const int wave = tid >> 6;
    const int wr = wave >> 1;        // n-half (64 rows)
    const int wc = wave & 1;         // j-half (32 cols)
    const int q  = lane >> 4;
    const int cl = lane & 15;

    // XCD-aware tile mapping: 2048 blocks, xcd = b&7; j sweeps fastest within
    // an XCD so 16 consecutive same-XCD blocks share one A-tile (L2-local).
    const int b   = blockIdx.x;
    const int xcd = b & 7;
    const int l   = b >> 3;          // 0..255
    const int jt  = l & 15;
    const int ntl = l >> 4;          // 0..15
    const int j0  = jt * BN;
    const int n0  = (xcd * 16 + ntl) * BM;

    // --- staging addresses ---
    const int rl = lane >> 3;        // row within an 8-row issue group
    const int p  = lane & 7;         // chunk slot this lane fills
    const int cf = (p ^ rl) * 8;     // fetched chunk's column (swz(r) = r&7 = rl)
    const bf16_t* gA[4];
    bf16_t* lA[4];
#pragma unroll
    for (int i = 0; i < 4; i++) {    // A: wave covers rows [wave*32, wave*32+32)
        const int r = wave * 32 + i * 8 + rl;
        gA[i] = hbf + (size_t)(n0 + r) * MEM_DIM + cf;
        lA[i] = &sA[(wave * 32 + i * 8) * BK];
    }
    const bf16_t* gB[2];
    bf16_t* lB[2];
#pragma unroll
    for (int i = 0; i < 2; i++) {    // B: wave covers rows [wave*16, wave*16+16)
        const int r = wave * 16 + i * 8 + rl;
        gB[i] = wbf + (size_t)(j0 + r) * MEM_DIM + cf;
        lB[i] = &sB[(wave * 16 + i * 8) * BK];
    }

    f32x4 acc[4][2];
#pragma unroll
    for (int a = 0; a < 4; a++)
#pragma unroll
        for (int c = 0; c < 2; c++) acc[a][c] = (f32x4)0.0f;

    // --- main K-loop: iterations 0..KITERS-2 ---
#pragma unroll 1
    for (int k = 0; k < KITERS - 1; ++k) {
#pragma unroll
        for (int i = 0; i < 4; i++) { async_load16(gA[i], lA[i]); gA[i] += BK; }
#pragma unroll
        for (int i = 0; i < 2; i++) { async_load16(gB[i], lB[i]); gB[i] += BK; }
        __syncthreads();   // drain: LDS tiles ready

#pragma unroll
        for (int h = 0; h < 2; h++) {
            bf16x8 af[4], bfr[2];
#pragma unroll
            for (int mt = 0; mt < 4; mt++) {
                const int ra = wr * 64 + mt * 16 + cl;
                af[mt] = *(const bf16x8*)(&sA[ra * BK + (((4 * h + q) ^ (cl & 7)) * 8)]);
            }
#pragma unroll
            for (int nt = 0; nt < 2; nt++) {
                const int rb = wc * 32 + nt * 16 + cl;
                bfr[nt] = *(const bf16x8*)(&sB[rb * BK + (((4 * h + q) ^ (cl & 7)) * 8)]);
            }
#pragma unroll
            for (int mt = 0; mt < 4; mt++)
#pragma unroll
                for (int nt = 0; nt < 2; nt++)
                    acc[mt][nt] = __builtin_amdgcn_mfma_f32_16x16x32_bf16(
                        af[mt], bfr[nt], acc[mt][nt], 0, 0, 0);
        }
        __syncthreads();   // tiles consumed
    }

    // --- peeled last iteration: stage + child_c/bias prefetch share one drain ---
#pragma unroll
    for (int i = 0; i < 4; i++) async_load16(gA[i], lA[i]);
#pragma unroll
    for (int i = 0; i < 2; i++) async_load16(gB[i], lB[i]);

    float ccr[2][4][4];
    float biasr[2];
    {
        const float* ccp = child_c + (size_t)(n0 + wr * 64 + q * 4) * MEM_DIM
                                   + j0 + wc * 32 + cl;
#pragma unroll
        for (int nt = 0; nt < 2; nt++) {
            biasr[nt] = b_fh[j0 + wc * 32 + nt * 16 + cl];
#pragma unroll
            for (int mt = 0; mt < 4; mt++)
#pragma unroll
                for (int r = 0; r < 4; r++)
                    ccr[nt][mt][r] = ccp[(size_t)(mt * 16 + r) * MEM_DIM + nt * 16];
        }
    }
    __syncthreads();   // drains staging AND child_c loads

#pragma unroll
    for (int h = 0; h < 2; h++) {
        bf16x8 af[4], bfr[2];
#pragma unroll
        for (int mt = 0; mt < 4; mt++) {
            const int ra = wr * 64 + mt * 16 + cl;
            af[mt] = *(const bf16x8*)(&sA[ra * BK + (((4 * h + q) ^ (cl & 7)) * 8)]);
        }
#pragma unroll
        for (int nt = 0; nt < 2; nt++) {
            const int rb = wc * 32 + nt * 16 + cl;
            bfr[nt] = *(const bf16x8*)(&sB[rb * BK + (((4 * h + q) ^ (cl & 7)) * 8)]);
        }
#pragma unroll
        for (int mt = 0; mt < 4; mt++)
#pragma unroll
            for (int nt = 0; nt < 2; nt++)
                acc[mt][nt] = __builtin_amdgcn_mfma_f32_16x16x32_bf16(
                    af[mt], bfr[nt], acc[mt][nt], 0, 0, 0);
    }

    // --- epilogue: f = sigmoid(S+b), colsum over 128 rows — all operands in regs ---
    if (tid < BN) sred[tid] = 0.0f;
    __syncthreads();

    float colsum[2] = {0.f, 0.f};
#pragma unroll
    for (int nt = 0; nt < 2; nt++) {
#pragma unroll
        for (int mt = 0; mt < 4; mt++) {
#pragma unroll
            for (int r = 0; r < 4; r++) {
                // C/D layout: col = lane&15, row = q*4 + r
                float s = acc[mt][nt][r] + biasr[nt];
                float fg = 1.0f / (1.0f + __expf(-s));
                colsum[nt] += fg * ccr[nt][mt][r];
            }
        }
        colsum[nt] += __shfl_xor(colsum[nt], 16, 64);
        colsum[nt] += __shfl_xor(colsum[nt], 32, 64);
    }
    if (q == 0) {
#pragma unroll
        for (int nt = 0; nt < 2; nt++)
            atomicAdd(&sred[wc * 32 + nt * 16 + cl], colsum[nt]);
    }
    __syncthreads();
    if (tid < BN) atomicAdd(&acc_c[j0 + tid], sred[tid]);
}

// ---------------- Kernel 2: finalize c, h ----------------
__global__ void finalize_kernel(const float* __restrict__ acc_c,
                                const float* __restrict__ o_ws,
                                float* __restrict__ out) {
    int t = blockIdx.x * 256 + threadIdx.x;
    if (t < MEM_DIM) {
        float cv = acc_c[t];
        float hv = o_ws[t] * tanhf(cv);
        out[t] = cv;
        out[MEM_DIM + t] = hv;
    }
}

// ---------------- Fallback path (ws too small) ----------------
__global__ void gates_kernel(const float* __restrict__ hsum,
                             const float* __restrict__ W_ih, const float* __restrict__ b_ih,
                             const float* __restrict__ W_uh, const float* __restrict__ b_uh,
                             const float* __restrict__ W_oh, const float* __restrict__ b_oh,
                             float* __restrict__ acc_c, float* __restrict__ o_ws) {
    const int j = blockIdx.x;
    const int tid = threadIdx.x;
    const float* wi = W_ih + (size_t)j * MEM_DIM;
    const float* wu = W_uh + (size_t)j * MEM_DIM;
    const float* wo = W_oh + (size_t)j * MEM_DIM;
    float si = 0.f, su = 0.f, so = 0.f;
    for (int k = tid; k < MEM_DIM; k += 256) {
        float hv = hsum[k];
        si += wi[k] * hv;
        su += wu[k] * hv;
        so += wo[k] * hv;
    }
    for (int off = 32; off > 0; off >>= 1) {
        si += __shfl_down(si, off, 64);
        su += __shfl_down(su, off, 64);
        so += __shfl_down(so, off, 64);
    }
    __shared__ float red[3][4];
    const int wave = tid >> 6, lane = tid & 63;
    if (lane == 0) { red[0][wave] = si; red[1][wave] = su; red[2][wave] = so; }
    __syncthreads();
    if (tid == 0) {
        float ti = red[0][0] + red[0][1] + red[0][2] + red[0][3] + b_ih[j];
        float tu = red[1][0] + red[1][1] + red[1][2] + red[1][3] + b_uh[j];
        float to = red[2][0] + red[2][1] + red[2][2] + red[2][3] + b_oh[j];
        acc_c[j] = (1.f / (1.f + expf(-ti))) * tanhf(tu);
        o_ws[j]  = 1.f / (1.f + expf(-to));
    }
}

#define LDS_STRIDE 40
__global__ __launch_bounds__(256) void fused_gemm_f32(
        const float* __restrict__ child_h, const float* __restrict__ child_c,
        const float* __restrict__ W_fh, const float* __restrict__ b_fh,
        float* __restrict__ acc_c) {
    __shared__ __align__(16) bf16_t sA[128 * LDS_STRIDE];
    __shared__ __align__(16) bf16_t sB[128 * LDS_STRIDE];
    __shared__ float sred[128];
    const int tid = threadIdx.x, lane = tid & 63, wave = tid >> 6;
    const int wr = wave >> 1, wc = wave & 1;
    const int j0 = blockIdx.x * 128, n0 = blockIdx.y * 128;
    const int q = lane >> 4, cl = lane & 15;
    f32x4 acc[4][4];
#pragma unroll
    for (int a = 0; a < 4; a++)
#pragma unroll
        for (int c = 0; c < 4; c++) acc[a][c] = (f32x4)0.0f;
    for (int k0 = 0; k0 < MEM_DIM; k0 += 32) {
#pragma unroll
        for (int i = 0; i < 4; i++) {
            int f = tid + i * 256, row = f >> 3, col = (f & 7) * 4;
            float4 va = *(const float4*)(child_h + (size_t)(n0 + row) * MEM_DIM + k0 + col);
            float4 vb = *(const float4*)(W_fh    + (size_t)(j0 + row) * MEM_DIM + k0 + col);
            bf16x4 ba = { (bf16_t)va.x, (bf16_t)va.y, (bf16_t)va.z, (bf16_t)va.w };
            bf16x4 bb = { (bf16_t)vb.x, (bf16_t)vb.y, (bf16_t)vb.z, (bf16_t)vb.w };
            *(bf16x4*)(&sA[row * LDS_STRIDE + col]) = ba;
            *(bf16x4*)(&sB[row * LDS_STRIDE + col]) = bb;
        }
        __syncthreads();
        bf16x8 af[4], bfr[4];
#pragma unroll
        for (int mt = 0; mt < 4; mt++) {
            af[mt]  = *(const bf16x8*)(&sA[(wr * 64 + mt * 16 + cl) * LDS_STRIDE + q * 8]);
            bfr[mt] = *(const bf16x8*)(&sB[(wc * 64 + mt * 16 + cl) * LDS_STRIDE + q * 8]);
        }
#pragma unroll
        for (int mt = 0; mt < 4; mt++)
#pragma unroll
            for (int nt = 0; nt < 4; nt++)
                acc[mt][nt] = __builtin_amdgcn_mfma_f32_16x16x32_bf16(af[mt], bfr[nt], acc[mt][nt], 0, 0, 0);
        __syncthreads();
    }
    if (tid < 128) sred[tid] = 0.0f;
    __syncthreads();
    float colsum[4] = {0.f, 0.f, 0.f, 0.f};
#pragma unroll
    for (int nt = 0; nt < 4; nt++) {
        const int col = j0 + wc * 64 + nt * 16 + cl;
        const float bias = b_fh[col];
#pragma unroll
        for (int mt = 0; mt < 4; mt++)
#pragma unroll
            for (int r = 0; r < 4; r++) {
                const int row = n0 + wr * 64 + mt * 16 + q * 4 + r;
                float s = acc[mt][nt][r] + bias;
                float fg = 1.0f / (1.0f + __expf(-s));
                colsum[nt] += fg * child_c[(size_t)row * MEM_DIM + col];
            }
        colsum[nt] += __shfl_xor(colsum[nt], 16, 64);
        colsum[nt] += __shfl_xor(colsum[nt], 32, 64);
    }
    if (q == 0)
#pragma unroll
        for (int nt = 0; nt < 4; nt++)
            atomicAdd(&sred[wc * 64 + nt * 16 + cl], colsum[nt]);
    __syncthreads();
    if (tid < 128) atomicAdd(&acc_c[j0 + tid], sred[tid]);
}

extern "C" void kernel_launch(void* const* d_in, const int* in_sizes, int n_in,
                              void* d_out, int out_size, void* d_ws, size_t ws_size,
                              hipStream_t stream) {
    const float* child_c = (const float*)d_in[0];
    const float* child_h = (const float*)d_in[1];
    const float* hsum    = (const float*)d_in[2];
    const float* W_ih    = (const float*)d_in[3];
    const float* b_ih    = (const float*)d_in[4];
    const float* W_fh    = (const float*)d_in[5];
    const float* b_fh    = (const float*)d_in[6];
    const float* W_uh    = (const float*)d_in[7];
    const float* b_uh    = (const float*)d_in[8];
    const float* W_oh    = (const float*)d_in[9];
    const float* b_oh    = (const float*)d_in[10];
    float* out   = (float*)d_out;

    float* acc_c = (float*)d_ws;                         // 1024 f
    float* o_ws  = acc_c + MEM_DIM;                      // 1024 f
    const size_t HBF_OFF   = 8192;                       // bytes
    const size_t HBF_BYTES = (size_t)N_CHILD * MEM_DIM * 2;   // 33.5 MB
    const size_t WBF_BYTES = (size_t)MEM_DIM * MEM_DIM * 2;   // 2 MB
    const size_t NEED = HBF_OFF + HBF_BYTES + WBF_BYTES;

    if (ws_size >= NEED) {
        bf16_t* hbf = (bf16_t*)((char*)d_ws + HBF_OFF);
        bf16_t* wbf = hbf + (size_t)N_CHILD * MEM_DIM;
        const int n8 = (N_CHILD * MEM_DIM + MEM_DIM * MEM_DIM) / 8;  // 2,228,224
        const int cvtBlocks = (n8 + 255) / 256;                      // 8704
        prep_kernel<<<MEM_DIM + cvtBlocks, 256, 0, stream>>>(
            child_h, W_fh, hbf, n8,
            hsum, W_ih, b_ih, W_uh, b_uh, W_oh, b_oh, acc_c, o_ws);
        fused_gemm_bf16<<<(N_CHILD / BM) * (MEM_DIM / BN), 256, 0, stream>>>(
            hbf, wbf, child_c, b_fh, acc_c);
    } else {
        gates_kernel<<<MEM_DIM, 256, 0, stream>>>(hsum, W_ih, b_ih, W_uh, b_uh,
                                                  W_oh, b_oh, acc_c, o_ws);
        dim3 grid(MEM_DIM / 128, N_CHILD / 128);
        fused_gemm_f32<<<grid, 256, 0, stream>>>(child_h, child_c, W_fh, b_fh, acc_c);
    }
    finalize_kernel<<<(MEM_DIM + 255) / 256, 256, 0, stream>>>(acc_c, o_ws, out);
}